// Round 1
// baseline (7012.946 us; speedup 1.0000x reference)
//
#include <hip/hip_runtime.h>
#include <cmath>

#define B_ 8
#define T_ 2048
#define BT_ 16384
#define D_ 512
#define H_ 1536
#define CM_ 192
#define NFFT_ 1024
#define NF_ 513
#define HOP_ 256
#define NO2_ 1026
#define OPAD_ 1056
#define LOUT_ 524032

__device__ __forceinline__ float gelu_f(float v) {
    return 0.5f * v * (1.0f + erff(v * 0.70710678118654752f));
}

// ---------------- small prep kernels ----------------

// embed_w (D, Cm, 7) -> wte[(c*7+k)*D + d]
__global__ __launch_bounds__(256) void k_transpose_w(const float* __restrict__ w,
                                                     float* __restrict__ wt) {
    int idx = blockIdx.x * 256 + threadIdx.x;
    if (idx >= CM_ * 7 * D_) return;
    int d  = idx & (D_ - 1);
    int ck = idx >> 9;
    wt[idx] = w[(size_t)d * (CM_ * 7) + ck];
}

// wmat (NFFT x OPAD): [n][f] = cos_b[n][f] (f<513), -sin_b[n][f-513] (513<=f<1026), 0 pad
__global__ __launch_bounds__(256) void k_build_wmat(float* __restrict__ wmat) {
    int idx = blockIdx.x * 256 + threadIdx.x;
    if (idx >= NFFT_ * OPAD_) return;
    int n = idx / OPAD_;
    int f = idx - n * OPAD_;
    float v = 0.0f;
    if (f < NF_) {
        int r = (n * f) & (NFFT_ - 1);
        float sc = (f == 0 || f == NF_ - 1) ? (1.0f / NFFT_) : (2.0f / NFFT_);
        v = cospif((float)r * (2.0f / NFFT_)) * sc;
    } else if (f < NO2_) {
        int f2 = f - NF_;
        int r = (n * f2) & (NFFT_ - 1);
        float sc = (f2 == 0 || f2 == NF_ - 1) ? (1.0f / NFFT_) : (2.0f / NFFT_);
        v = -sinpif((float)r * (2.0f / NFFT_)) * sc;
    }
    wmat[idx] = v;
}

// ---------------- embed conv (GEMM-like, K = 192 channels x 7 taps) ----------------
// out x[bt][d] = sum_c sum_k mel[b][c][t+k-3] * wte[(c*7+k)*D + d] + bias[d]
__global__ __launch_bounds__(256) void k_embed(const float* __restrict__ mel,
                                               const float* __restrict__ wt,
                                               const float* __restrict__ bias,
                                               float* __restrict__ x) {
    __shared__ float mel_s[134];
    __shared__ float ws_s[7][128];
    int tid = threadIdx.x;
    int tileM = blockIdx.x & 127;
    int tileN = blockIdx.x >> 7;
    int bm = tileM * 128;      // global (b,t) row
    int b  = bm >> 11;
    int t0 = bm & (T_ - 1);
    int bn = tileN * 128;
    int tm = (tid >> 4) << 3;
    int tn = (tid & 15) << 3;
    float acc[8][8];
#pragma unroll
    for (int i = 0; i < 8; ++i)
#pragma unroll
        for (int j = 0; j < 8; ++j) acc[i][j] = 0.0f;

    const float* melb = mel + (size_t)b * CM_ * T_;
    for (int c = 0; c < CM_; ++c) {
        if (tid < 134) {
            int t = t0 - 3 + tid;
            mel_s[tid] = (t >= 0 && t < T_) ? melb[(size_t)c * T_ + t] : 0.0f;
        }
#pragma unroll
        for (int it = 0; it < 4; ++it) {
            int id2 = tid + it * 256;
            if (id2 < 896) {
                int k = id2 >> 7;
                int n = id2 & 127;
                ws_s[k][n] = wt[(size_t)(c * 7 + k) * D_ + bn + n];
            }
        }
        __syncthreads();
#pragma unroll
        for (int k = 0; k < 7; ++k) {
            float a[8], bb[8];
#pragma unroll
            for (int i = 0; i < 8; ++i) a[i] = mel_s[tm + i + k];
            *(float4*)&bb[0] = *(const float4*)&ws_s[k][tn];
            *(float4*)&bb[4] = *(const float4*)&ws_s[k][tn + 4];
#pragma unroll
            for (int i = 0; i < 8; ++i)
#pragma unroll
                for (int j = 0; j < 8; ++j) acc[i][j] = fmaf(a[i], bb[j], acc[i][j]);
        }
        __syncthreads();
    }
#pragma unroll
    for (int i = 0; i < 8; ++i) {
        size_t m = bm + tm + i;
#pragma unroll
        for (int j = 0; j < 8; j += 4) {
            int n = bn + tn + j;
            float4 v;
            v.x = acc[i][j + 0] + bias[n + 0];
            v.y = acc[i][j + 1] + bias[n + 1];
            v.z = acc[i][j + 2] + bias[n + 2];
            v.w = acc[i][j + 3] + bias[n + 3];
            *(float4*)&x[m * D_ + n] = v;
        }
    }
}

// ---------------- LayerNorm over D=512, one wave per row ----------------
__global__ __launch_bounds__(64) void k_ln(const float* __restrict__ in,
                                           float* __restrict__ out,
                                           const float* __restrict__ w,
                                           const float* __restrict__ b) {
    int row = blockIdx.x;
    int lane = threadIdx.x;
    const float* p = in + (size_t)row * D_ + lane * 8;
    float4 v0 = *(const float4*)p;
    float4 v1 = *(const float4*)(p + 4);
    float s  = v0.x + v0.y + v0.z + v0.w + v1.x + v1.y + v1.z + v1.w;
    float ss = v0.x * v0.x + v0.y * v0.y + v0.z * v0.z + v0.w * v0.w +
               v1.x * v1.x + v1.y * v1.y + v1.z * v1.z + v1.w * v1.w;
#pragma unroll
    for (int off = 32; off > 0; off >>= 1) {
        s  += __shfl_xor(s, off);
        ss += __shfl_xor(ss, off);
    }
    float mean = s * (1.0f / 512.0f);
    float var  = ss * (1.0f / 512.0f) - mean * mean;
    float rs = rsqrtf(var + 1e-5f);
    const float* wp = w + lane * 8;
    const float* bp = b + lane * 8;
    float4 w0 = *(const float4*)wp, w1 = *(const float4*)(wp + 4);
    float4 b0 = *(const float4*)bp, b1 = *(const float4*)(bp + 4);
    float4 o0, o1;
    o0.x = (v0.x - mean) * rs * w0.x + b0.x;
    o0.y = (v0.y - mean) * rs * w0.y + b0.y;
    o0.z = (v0.z - mean) * rs * w0.z + b0.z;
    o0.w = (v0.w - mean) * rs * w0.w + b0.w;
    o1.x = (v1.x - mean) * rs * w1.x + b1.x;
    o1.y = (v1.y - mean) * rs * w1.y + b1.y;
    o1.z = (v1.z - mean) * rs * w1.z + b1.z;
    o1.w = (v1.w - mean) * rs * w1.w + b1.w;
    float* q = out + (size_t)row * D_ + lane * 8;
    *(float4*)q = o0;
    *(float4*)(q + 4) = o1;
}

// ---------------- depthwise conv k=7 over t, (B,T,D) layout ----------------
__global__ __launch_bounds__(256) void k_dwconv(const float* __restrict__ x,
                                                const float* __restrict__ dw,
                                                const float* __restrict__ db,
                                                float* __restrict__ y) {
    int idx = blockIdx.x * 256 + threadIdx.x;   // over BT_*D_
    int d  = idx & (D_ - 1);
    int bt = idx >> 9;
    int t  = bt & (T_ - 1);
    int base = bt - t;                           // b*T_
    float acc = db[d];
#pragma unroll
    for (int k = 0; k < 7; ++k) {
        int tt = t + k - 3;
        if (tt >= 0 && tt < T_)
            acc = fmaf(dw[d * 7 + k], x[((size_t)(base + tt) << 9) + d], acc);
    }
    y[idx] = acc;
}

// ---------------- generic tiled fp32 GEMM: C(MxN) = A(MxK) . W(NxK)^T ----------------
// EPI: 0 = +bias ; 1 = gelu(+bias) ; 2 = resid: C += gamma*( +bias) ; 3 = *bias (window)
template <int EPI>
__device__ __forceinline__ float epi_val(float v, int n, const float* bias) {
    if constexpr (EPI == 0) return v + bias[n];
    else if constexpr (EPI == 1) return gelu_f(v + bias[n]);
    else if constexpr (EPI == 3) return v * bias[n];
    else return v + bias[n];
}

template <int EPI>
__global__ __launch_bounds__(256) void k_gemm(const float* __restrict__ A,
                                              const float* __restrict__ W,
                                              const float* __restrict__ bias,
                                              const float* __restrict__ gamma,
                                              float* __restrict__ C,
                                              int M, int N, int K, int ldc) {
    __shared__ float As[16][132];
    __shared__ float Ws[16][132];
    int tid = threadIdx.x;
    int nMt = M >> 7;
    int bm = (blockIdx.x % nMt) << 7;
    int bn = (blockIdx.x / nMt) << 7;
    int tm = (tid >> 4) << 3;
    int tn = (tid & 15) << 3;
    float acc[8][8];
#pragma unroll
    for (int i = 0; i < 8; ++i)
#pragma unroll
        for (int j = 0; j < 8; ++j) acc[i][j] = 0.0f;

    for (int k0 = 0; k0 < K; k0 += 16) {
#pragma unroll
        for (int i = 0; i < 2; ++i) {
            int idx = tid + (i << 8);
            int row = idx >> 2;
            int c4  = (idx & 3) << 2;
            float4 v = *(const float4*)(A + (size_t)(bm + row) * K + k0 + c4);
            As[c4 + 0][row] = v.x; As[c4 + 1][row] = v.y;
            As[c4 + 2][row] = v.z; As[c4 + 3][row] = v.w;
        }
#pragma unroll
        for (int i = 0; i < 2; ++i) {
            int idx = tid + (i << 8);
            int row = idx >> 2;
            int c4  = (idx & 3) << 2;
            int n = bn + row;
            float4 v = make_float4(0.f, 0.f, 0.f, 0.f);
            if (n < N) v = *(const float4*)(W + (size_t)n * K + k0 + c4);
            Ws[c4 + 0][row] = v.x; Ws[c4 + 1][row] = v.y;
            Ws[c4 + 2][row] = v.z; Ws[c4 + 3][row] = v.w;
        }
        __syncthreads();
#pragma unroll
        for (int k = 0; k < 16; ++k) {
            float a[8], bb[8];
            *(float4*)&a[0]  = *(const float4*)&As[k][tm];
            *(float4*)&a[4]  = *(const float4*)&As[k][tm + 4];
            *(float4*)&bb[0] = *(const float4*)&Ws[k][tn];
            *(float4*)&bb[4] = *(const float4*)&Ws[k][tn + 4];
#pragma unroll
            for (int i = 0; i < 8; ++i)
#pragma unroll
                for (int j = 0; j < 8; ++j) acc[i][j] = fmaf(a[i], bb[j], acc[i][j]);
        }
        __syncthreads();
    }

    bool ragged = (bn + 128 > N);
#pragma unroll
    for (int i = 0; i < 8; ++i) {
        size_t moff = (size_t)(bm + tm + i) * ldc;
        if constexpr (EPI == 2) {
#pragma unroll
            for (int j = 0; j < 8; j += 4) {
                int n = bn + tn + j;
                float4 r = *(float4*)(C + moff + n);
                r.x += gamma[n + 0] * (acc[i][j + 0] + bias[n + 0]);
                r.y += gamma[n + 1] * (acc[i][j + 1] + bias[n + 1]);
                r.z += gamma[n + 2] * (acc[i][j + 2] + bias[n + 2]);
                r.w += gamma[n + 3] * (acc[i][j + 3] + bias[n + 3]);
                *(float4*)(C + moff + n) = r;
            }
        } else if (!ragged) {
#pragma unroll
            for (int j = 0; j < 8; j += 4) {
                int n = bn + tn + j;
                float4 v;
                v.x = epi_val<EPI>(acc[i][j + 0], n + 0, bias);
                v.y = epi_val<EPI>(acc[i][j + 1], n + 1, bias);
                v.z = epi_val<EPI>(acc[i][j + 2], n + 2, bias);
                v.w = epi_val<EPI>(acc[i][j + 3], n + 3, bias);
                *(float4*)(C + moff + n) = v;
            }
        } else {
#pragma unroll
            for (int j = 0; j < 8; ++j) {
                int n = bn + tn + j;
                if (n < N) C[moff + n] = epi_val<EPI>(acc[i][j], n, bias);
                else if (n < ldc) C[moff + n] = 0.0f;   // zero the K-pad columns
            }
        }
    }
}

// ---------------- head output -> S_real | S_imag (in place, stride OPAD) ----------------
__global__ __launch_bounds__(256) void k_srsi(float* __restrict__ o) {
    int idx = blockIdx.x * 256 + threadIdx.x;   // BT_*NF_
    if (idx >= BT_ * NF_) return;
    int m = idx / NF_;
    int f = idx - m * NF_;
    size_t base = (size_t)m * OPAD_;
    float mag = fminf(expf(o[base + f]), 100.0f);
    float ph = o[base + NF_ + f];
    float sn, cs;
    sincosf(ph, &sn, &cs);
    o[base + f]       = mag * cs;
    o[base + NF_ + f] = mag * sn;
}

// ---------------- overlap-add + win_env + crop (deterministic gather) ----------------
__global__ __launch_bounds__(256) void k_gather(const float* __restrict__ frames,
                                                const float* __restrict__ win,
                                                float* __restrict__ out) {
    int idx = blockIdx.x * 256 + threadIdx.x;   // B_*LOUT_
    int b  = idx / LOUT_;
    int lp = idx - b * LOUT_;
    int l = lp + (NFFT_ / 2);
    int thi = l >> 8;                 // l / HOP_
    if (thi > T_ - 1) thi = T_ - 1;
    int tlo = l - (NFFT_ - 1) + (HOP_ - 1);
    tlo = (tlo < 0) ? 0 : (tlo >> 8);
    float num = 0.0f, den = 0.0f;
    for (int t = tlo; t <= thi; ++t) {
        int n = l - (t << 8);
        float wv = win[n];
        num += frames[((size_t)(b * T_ + t) << 10) + n];
        den = fmaf(wv, wv, den);
    }
    out[idx] = num / (den + 1e-11f);
}

// ---------------- launch ----------------
extern "C" void kernel_launch(void* const* d_in, const int* in_sizes, int n_in,
                              void* d_out, int out_size, void* d_ws, size_t ws_size,
                              hipStream_t stream) {
    (void)in_sizes; (void)n_in; (void)out_size; (void)ws_size;
    const float* mel     = (const float*)d_in[0];
    const float* embed_w = (const float*)d_in[1];
    const float* embed_b = (const float*)d_in[2];
    const float* norm_w  = (const float*)d_in[3];
    const float* norm_b  = (const float*)d_in[4];
    const float* bdw = (const float*)d_in[5];
    const float* bdb = (const float*)d_in[6];
    const float* bnw = (const float*)d_in[7];
    const float* bnb = (const float*)d_in[8];
    const float* bw1 = (const float*)d_in[9];
    const float* bb1 = (const float*)d_in[10];
    const float* bw2 = (const float*)d_in[11];
    const float* bb2 = (const float*)d_in[12];
    const float* bg  = (const float*)d_in[13];
    const float* fnw = (const float*)d_in[14];
    const float* fnb = (const float*)d_in[15];
    const float* hw  = (const float*)d_in[16];
    const float* hb  = (const float*)d_in[17];
    const float* win = (const float*)d_in[18];

    float* ws = (float*)d_ws;
    float* xbuf = ws;                              // BT_*D_
    float* ybuf = xbuf + (size_t)BT_ * D_;         // BT_*D_
    float* hbuf = ybuf + (size_t)BT_ * D_;         // BT_*H_
    float* obuf = hbuf;                            // BT_*OPAD_ (reuses hbuf)
    float* frames = xbuf;                          // BT_*NFFT_ (reuses xbuf+ybuf)
    float* wmat = hbuf + (size_t)BT_ * H_;         // NFFT_*OPAD_
    float* wte  = wmat + (size_t)NFFT_ * OPAD_;    // CM_*7*D_

    k_transpose_w<<<(CM_ * 7 * D_ + 255) / 256, 256, 0, stream>>>(embed_w, wte);
    k_build_wmat<<<(NFFT_ * OPAD_ + 255) / 256, 256, 0, stream>>>(wmat);

    k_embed<<<512, 256, 0, stream>>>(mel, wte, embed_b, xbuf);
    k_ln<<<BT_, 64, 0, stream>>>(xbuf, xbuf, norm_w, norm_b);

    for (int bl = 0; bl < 8; ++bl) {
        k_dwconv<<<BT_ * D_ / 256, 256, 0, stream>>>(xbuf, bdw + bl * D_ * 7, bdb + bl * D_, ybuf);
        k_ln<<<BT_, 64, 0, stream>>>(ybuf, ybuf, bnw + bl * D_, bnb + bl * D_);
        k_gemm<1><<<128 * (H_ / 128), 256, 0, stream>>>(ybuf, bw1 + (size_t)bl * H_ * D_,
                                                        bb1 + bl * H_, nullptr, hbuf,
                                                        BT_, H_, D_, H_);
        k_gemm<2><<<128 * (D_ / 128), 256, 0, stream>>>(hbuf, bw2 + (size_t)bl * D_ * H_,
                                                        bb2 + bl * D_, bg + bl * D_, xbuf,
                                                        BT_, D_, H_, D_);
    }

    k_ln<<<BT_, 64, 0, stream>>>(xbuf, ybuf, fnw, fnb);
    k_gemm<0><<<128 * 9, 256, 0, stream>>>(ybuf, hw, hb, nullptr, obuf,
                                           BT_, NO2_, D_, OPAD_);
    k_srsi<<<BT_ * NF_ / 256, 256, 0, stream>>>(obuf);
    k_gemm<3><<<128 * (NFFT_ / 128), 256, 0, stream>>>(obuf, wmat, win, nullptr, frames,
                                                       BT_, NFFT_, OPAD_, NFFT_);
    k_gather<<<B_ * LOUT_ / 256, 256, 0, stream>>>(frames, win, (float*)d_out);
}

// Round 2
// 1495.121 us; speedup vs baseline: 4.6906x; 4.6906x over previous
//
#include <hip/hip_runtime.h>
#include <cmath>

#define B_ 8
#define T_ 2048
#define BT_ 16384
#define D_ 512
#define H_ 1536
#define CM_ 192
#define KE_ 1344      // im2col K = 192*7
#define NFFT_ 1024
#define NF_ 513
#define HOP_ 256
#define NO2_ 1026
#define NPAD_ 1152    // head N padded to tile multiple
#define KI_ 1056      // ISTFT K (= 1026 padded to 32)
#define LOUT_ 524032

typedef _Float16 f16;
typedef f16 f16x8 __attribute__((ext_vector_type(8)));
typedef float f32x4 __attribute__((ext_vector_type(4)));

__device__ __forceinline__ float gelu_f(float v) {
    return 0.5f * v * (1.0f + erff(v * 0.70710678118654752f));
}

__device__ __forceinline__ void gload16(const void* g, void* s) {
    __builtin_amdgcn_global_load_lds((const __attribute__((address_space(1))) void*)g,
                                     (__attribute__((address_space(3))) void*)s, 16, 0, 0);
}

// ---------------- conversion / prep kernels ----------------

__global__ __launch_bounds__(256) void k_cvt(const float* __restrict__ src,
                                             f16* __restrict__ dst, int n) {
    int i = blockIdx.x * 256 + threadIdx.x;
    if (i < n) dst[i] = (f16)src[i];
}

// head weights (1026,512) -> fp16 (1152,512) zero-padded rows
__global__ __launch_bounds__(256) void k_cvt_head(const float* __restrict__ src,
                                                  f16* __restrict__ dst) {
    int i = blockIdx.x * 256 + threadIdx.x;
    if (i >= NPAD_ * D_) return;
    int row = i >> 9;
    dst[i] = (row < NO2_) ? (f16)src[i] : (f16)0.0f;
}

__global__ __launch_bounds__(256) void k_pad_hb(const float* __restrict__ src,
                                                float* __restrict__ dst) {
    int i = blockIdx.x * 256 + threadIdx.x;
    if (i < NPAD_) dst[i] = (i < NO2_) ? src[i] : 0.0f;
}

// ISTFT basis fp16: wmat[n][f2], f2<513: cos*scale ; 513..1025: -sin*scale ; pad 0
__global__ __launch_bounds__(256) void k_build_wmat(f16* __restrict__ wmat) {
    int idx = blockIdx.x * 256 + threadIdx.x;
    if (idx >= NFFT_ * KI_) return;
    int n = idx / KI_;
    int f2 = idx - n * KI_;
    float v = 0.0f;
    if (f2 < NF_) {
        int r = (n * f2) & (NFFT_ - 1);
        float sc = (f2 == 0 || f2 == NF_ - 1) ? (1.0f / NFFT_) : (2.0f / NFFT_);
        v = cospif((float)r * (2.0f / NFFT_)) * sc;
    } else if (f2 < NO2_) {
        int f = f2 - NF_;
        int r = (n * f) & (NFFT_ - 1);
        float sc = (f == 0 || f == NF_ - 1) ? (1.0f / NFFT_) : (2.0f / NFFT_);
        v = -sinpif((float)r * (2.0f / NFFT_)) * sc;
    }
    wmat[idx] = (f16)v;
}

// im2col for embed conv: A[bt][c*7+k] = mel[b][c][t+k-3]
__global__ __launch_bounds__(256) void k_im2col(const float* __restrict__ mel,
                                                f16* __restrict__ A) {
    int idx = blockIdx.x * 256 + threadIdx.x;
    if (idx >= BT_ * KE_) return;
    int bt = idx / KE_;
    int ck = idx - bt * KE_;
    int c = ck / 7;
    int kk = ck - c * 7;
    int b = bt >> 11;
    int t = bt & (T_ - 1);
    int tt = t + kk - 3;
    float v = (tt >= 0 && tt < T_) ? mel[((size_t)b * CM_ + c) * T_ + tt] : 0.0f;
    A[idx] = (f16)v;
}

// ---------------- LayerNorm over D=512, one wave per row ----------------
template <bool HOUT>
__global__ __launch_bounds__(64) void k_ln(const float* __restrict__ in,
                                           void* __restrict__ out,
                                           const float* __restrict__ w,
                                           const float* __restrict__ b) {
    int row = blockIdx.x;
    int lane = threadIdx.x;
    const float* p = in + (size_t)row * D_ + lane * 8;
    float4 v0 = *(const float4*)p;
    float4 v1 = *(const float4*)(p + 4);
    float s  = v0.x + v0.y + v0.z + v0.w + v1.x + v1.y + v1.z + v1.w;
    float ss = v0.x * v0.x + v0.y * v0.y + v0.z * v0.z + v0.w * v0.w +
               v1.x * v1.x + v1.y * v1.y + v1.z * v1.z + v1.w * v1.w;
#pragma unroll
    for (int off = 32; off > 0; off >>= 1) {
        s  += __shfl_xor(s, off);
        ss += __shfl_xor(ss, off);
    }
    float mean = s * (1.0f / 512.0f);
    float var  = ss * (1.0f / 512.0f) - mean * mean;
    float rs = rsqrtf(var + 1e-5f);
    const float* wp = w + lane * 8;
    const float* bp = b + lane * 8;
    float4 w0 = *(const float4*)wp, w1 = *(const float4*)(wp + 4);
    float4 b0 = *(const float4*)bp, b1 = *(const float4*)(bp + 4);
    float o[8];
    o[0] = (v0.x - mean) * rs * w0.x + b0.x;
    o[1] = (v0.y - mean) * rs * w0.y + b0.y;
    o[2] = (v0.z - mean) * rs * w0.z + b0.z;
    o[3] = (v0.w - mean) * rs * w0.w + b0.w;
    o[4] = (v1.x - mean) * rs * w1.x + b1.x;
    o[5] = (v1.y - mean) * rs * w1.y + b1.y;
    o[6] = (v1.z - mean) * rs * w1.z + b1.z;
    o[7] = (v1.w - mean) * rs * w1.w + b1.w;
    if constexpr (HOUT) {
        f16x8 h;
#pragma unroll
        for (int i = 0; i < 8; ++i) h[i] = (f16)o[i];
        *(f16x8*)((f16*)out + (size_t)row * D_ + lane * 8) = h;
    } else {
        float* q = (float*)out + (size_t)row * D_ + lane * 8;
        *(float4*)q = make_float4(o[0], o[1], o[2], o[3]);
        *(float4*)(q + 4) = make_float4(o[4], o[5], o[6], o[7]);
    }
}

// ---------------- depthwise conv k=7 over t, (B,T,D) layout ----------------
__global__ __launch_bounds__(256) void k_dwconv(const float* __restrict__ x,
                                                const float* __restrict__ dw,
                                                const float* __restrict__ db,
                                                float* __restrict__ y) {
    int idx = blockIdx.x * 256 + threadIdx.x;
    int d  = idx & (D_ - 1);
    int bt = idx >> 9;
    int t  = bt & (T_ - 1);
    int base = bt - t;
    float acc = db[d];
#pragma unroll
    for (int k = 0; k < 7; ++k) {
        int tt = t + k - 3;
        if (tt >= 0 && tt < T_)
            acc = fmaf(dw[d * 7 + k], x[((size_t)(base + tt) << 9) + d], acc);
    }
    y[idx] = acc;
}

// ---------------- fp16 MFMA GEMM: C(MxN) = A(MxK) . W(NxK)^T ----------------
// EPI: 0 = fp32 +bias ; 1 = fp16 gelu(+bias) ; 2 = fp32 C += gamma*(v+bias) ; 3 = fp32 *bias
#define BM 128
#define BN 128
#define BK 32

__device__ __forceinline__ void stage_tile(const f16* __restrict__ A, const f16* __restrict__ W,
                                           f16* sA, f16* sB, int bm, int bn, int K, int kof,
                                           int tid) {
#pragma unroll
    for (int i = 0; i < 2; ++i) {
        int idx = (i << 8) + tid;
        int row = idx >> 2;
        int kc  = (idx & 3) << 3;
        gload16(A + (size_t)(bm + row) * K + kof + kc, sA + (idx << 3));
    }
#pragma unroll
    for (int i = 0; i < 2; ++i) {
        int idx = (i << 8) + tid;
        int row = idx >> 2;
        int kc  = (idx & 3) << 3;
        gload16(W + (size_t)(bn + row) * K + kof + kc, sB + (idx << 3));
    }
}

template <int EPI>
__global__ __launch_bounds__(256) void k_hgemm(const f16* __restrict__ A,
                                               const f16* __restrict__ W,
                                               const float* __restrict__ bias,
                                               const float* __restrict__ gamma,
                                               void* __restrict__ C,
                                               int M, int N, int K, int ldc) {
    __shared__ f16 sA[2][BM * BK];
    __shared__ f16 sB[2][BN * BK];
    int tid = threadIdx.x;
    int nMt = M >> 7;
    int bm = (blockIdx.x % nMt) << 7;
    int bn = (blockIdx.x / nMt) << 7;
    int lane = tid & 63;
    int lr = lane & 15;
    int lk = lane >> 4;
    int wv = tid >> 6;
    int wm = (wv >> 1) << 6;
    int wn = (wv & 1) << 6;

    f32x4 acc[4][4];
#pragma unroll
    for (int i = 0; i < 4; ++i)
#pragma unroll
        for (int j = 0; j < 4; ++j) acc[i][j] = {0.f, 0.f, 0.f, 0.f};

    int nk = K >> 5;
    f16* sAc = &sA[0][0]; f16* sAn = &sA[1][0];
    f16* sBc = &sB[0][0]; f16* sBn = &sB[1][0];

    stage_tile(A, W, sAc, sBc, bm, bn, K, 0, tid);
    __syncthreads();

    for (int kt = 0; kt < nk; ++kt) {
        if (kt + 1 < nk) stage_tile(A, W, sAn, sBn, bm, bn, K, (kt + 1) << 5, tid);
        f16x8 af[4], bf[4];
#pragma unroll
        for (int i = 0; i < 4; ++i)
            af[i] = *(const f16x8*)(sAc + ((wm + i * 16 + lr) << 5) + (lk << 3));
#pragma unroll
        for (int j = 0; j < 4; ++j)
            bf[j] = *(const f16x8*)(sBc + ((wn + j * 16 + lr) << 5) + (lk << 3));
#pragma unroll
        for (int i = 0; i < 4; ++i)
#pragma unroll
            for (int j = 0; j < 4; ++j)
                acc[i][j] = __builtin_amdgcn_mfma_f32_16x16x32_f16(af[i], bf[j], acc[i][j], 0, 0, 0);
        __syncthreads();
        f16* t0 = sAc; sAc = sAn; sAn = t0;
        f16* t1 = sBc; sBc = sBn; sBn = t1;
    }

    int lk4 = lk << 2;
#pragma unroll
    for (int i = 0; i < 4; ++i) {
#pragma unroll
        for (int r = 0; r < 4; ++r) {
            int row = bm + wm + i * 16 + lk4 + r;
            size_t moff = (size_t)row * ldc;
#pragma unroll
            for (int j = 0; j < 4; ++j) {
                int col = bn + wn + j * 16 + lr;
                float v = acc[i][j][r];
                if constexpr (EPI == 0) {
                    ((float*)C)[moff + col] = v + bias[col];
                } else if constexpr (EPI == 1) {
                    ((f16*)C)[moff + col] = (f16)gelu_f(v + bias[col]);
                } else if constexpr (EPI == 2) {
                    ((float*)C)[moff + col] += gamma[col] * (v + bias[col]);
                } else {
                    ((float*)C)[moff + col] = v * bias[col];
                }
            }
        }
    }
}

// ---------------- head fp32 (stride 1152) -> S fp16 (stride 1056, padded) ----------------
__global__ __launch_bounds__(256) void k_srsi(const float* __restrict__ o,
                                              f16* __restrict__ S) {
    int idx = blockIdx.x * 256 + threadIdx.x;
    if (idx >= BT_ * KI_) return;
    int m = idx / KI_;
    int f2 = idx - m * KI_;
    size_t base = (size_t)m * NPAD_;
    float v = 0.0f;
    if (f2 < NF_) {
        float mag = fminf(expf(o[base + f2]), 100.0f);
        float sn, cs;
        sincosf(o[base + NF_ + f2], &sn, &cs);
        v = mag * cs;
    } else if (f2 < NO2_) {
        int f = f2 - NF_;
        float mag = fminf(expf(o[base + f]), 100.0f);
        float sn, cs;
        sincosf(o[base + NF_ + f], &sn, &cs);
        v = mag * sn;
    }
    S[(size_t)m * KI_ + f2] = (f16)v;
}

// ---------------- overlap-add + win_env + crop (deterministic gather) ----------------
__global__ __launch_bounds__(256) void k_gather(const float* __restrict__ frames,
                                                const float* __restrict__ win,
                                                float* __restrict__ out) {
    int idx = blockIdx.x * 256 + threadIdx.x;
    int b  = idx / LOUT_;
    int lp = idx - b * LOUT_;
    int l = lp + (NFFT_ / 2);
    int thi = l >> 8;
    if (thi > T_ - 1) thi = T_ - 1;
    int tlo = l - (NFFT_ - 1) + (HOP_ - 1);
    tlo = (tlo < 0) ? 0 : (tlo >> 8);
    float num = 0.0f, den = 0.0f;
    for (int t = tlo; t <= thi; ++t) {
        int n = l - (t << 8);
        float wv = win[n];
        num += frames[((size_t)(b * T_ + t) << 10) + n];
        den = fmaf(wv, wv, den);
    }
    out[idx] = num / (den + 1e-11f);
}

// ---------------- launch ----------------
extern "C" void kernel_launch(void* const* d_in, const int* in_sizes, int n_in,
                              void* d_out, int out_size, void* d_ws, size_t ws_size,
                              hipStream_t stream) {
    (void)in_sizes; (void)n_in; (void)out_size; (void)ws_size;
    const float* mel     = (const float*)d_in[0];
    const float* embed_w = (const float*)d_in[1];
    const float* embed_b = (const float*)d_in[2];
    const float* norm_w  = (const float*)d_in[3];
    const float* norm_b  = (const float*)d_in[4];
    const float* bdw = (const float*)d_in[5];
    const float* bdb = (const float*)d_in[6];
    const float* bnw = (const float*)d_in[7];
    const float* bnb = (const float*)d_in[8];
    const float* bw1 = (const float*)d_in[9];
    const float* bb1 = (const float*)d_in[10];
    const float* bw2 = (const float*)d_in[11];
    const float* bb2 = (const float*)d_in[12];
    const float* bg  = (const float*)d_in[13];
    const float* fnw = (const float*)d_in[14];
    const float* fnb = (const float*)d_in[15];
    const float* hw  = (const float*)d_in[16];
    const float* hb  = (const float*)d_in[17];
    const float* win = (const float*)d_in[18];

    char* ws = (char*)d_ws;
    // region A: [0, 50.3MB): xbuf fp32 (33.5MB) + ybuf_h fp16 (16.8MB); S_h overlays it later
    float* xbuf   = (float*)ws;
    f16*   ybuf_h = (f16*)(ws + 33554432);
    f16*   S_h    = (f16*)ws;
    // region R: [50.3MB, 134.2MB): ybuf f32 + hbuf_h fp16; also A_h / obuf / frames
    char* R = ws + 50331648;
    float* ybuf   = (float*)R;
    f16*   hbuf_h = (f16*)(R + 33554432);
    f16*   A_h    = (f16*)R;
    float* obuf   = (float*)R;
    float* frames = (float*)R;
    // region W: [134.2MB, ...): converted weights
    char* Wr = ws + 134217728;
    f16*   w1_h   = (f16*)Wr;
    f16*   w2_h   = (f16*)(Wr + 12582912);
    f16*   head_h = (f16*)(Wr + 25165824);
    f16*   wmat_h = (f16*)(Wr + 26345472);
    f16*   we_h   = (f16*)(Wr + 28508160);
    float* hb_pad = (float*)(Wr + 29884416);

    const int nW1 = 8 * H_ * D_;
    k_cvt<<<(nW1 + 255) / 256, 256, 0, stream>>>(bw1, w1_h, nW1);
    k_cvt<<<(nW1 + 255) / 256, 256, 0, stream>>>(bw2, w2_h, nW1);
    k_cvt<<<(CM_ * 7 * D_ + 255) / 256, 256, 0, stream>>>(embed_w, we_h, CM_ * 7 * D_);
    k_cvt_head<<<(NPAD_ * D_ + 255) / 256, 256, 0, stream>>>(hw, head_h);
    k_pad_hb<<<5, 256, 0, stream>>>(hb, hb_pad);
    k_build_wmat<<<(NFFT_ * KI_ + 255) / 256, 256, 0, stream>>>(wmat_h);

    // embed conv as im2col + GEMM
    k_im2col<<<(BT_ * KE_ + 255) / 256, 256, 0, stream>>>(mel, A_h);
    k_hgemm<0><<<128 * (D_ / 128), 256, 0, stream>>>(A_h, we_h, embed_b, nullptr, xbuf,
                                                     BT_, D_, KE_, D_);
    k_ln<false><<<BT_, 64, 0, stream>>>(xbuf, xbuf, norm_w, norm_b);

    for (int bl = 0; bl < 8; ++bl) {
        k_dwconv<<<BT_ * D_ / 256, 256, 0, stream>>>(xbuf, bdw + bl * D_ * 7, bdb + bl * D_, ybuf);
        k_ln<true><<<BT_, 64, 0, stream>>>(ybuf, ybuf_h, bnw + bl * D_, bnb + bl * D_);
        k_hgemm<1><<<128 * (H_ / 128), 256, 0, stream>>>(ybuf_h, w1_h + (size_t)bl * H_ * D_,
                                                         bb1 + bl * H_, nullptr, hbuf_h,
                                                         BT_, H_, D_, H_);
        k_hgemm<2><<<128 * (D_ / 128), 256, 0, stream>>>(hbuf_h, w2_h + (size_t)bl * D_ * H_,
                                                         bb2 + bl * D_, bg + bl * D_, xbuf,
                                                         BT_, D_, H_, D_);
    }

    k_ln<true><<<BT_, 64, 0, stream>>>(xbuf, ybuf_h, fnw, fnb);
    k_hgemm<0><<<128 * (NPAD_ / 128), 256, 0, stream>>>(ybuf_h, head_h, hb_pad, nullptr, obuf,
                                                        BT_, NPAD_, D_, NPAD_);
    k_srsi<<<(BT_ * KI_ + 255) / 256, 256, 0, stream>>>(obuf, S_h);
    k_hgemm<3><<<128 * (NFFT_ / 128), 256, 0, stream>>>(S_h, wmat_h, win, nullptr, frames,
                                                        BT_, NFFT_, KI_, NFFT_);
    k_gather<<<B_ * LOUT_ / 256, 256, 0, stream>>>(frames, win, (float*)d_out);
}

// Round 3
// 1336.069 us; speedup vs baseline: 5.2489x; 1.1190x over previous
//
#include <hip/hip_runtime.h>
#include <cmath>

#define B_ 8
#define T_ 2048
#define BT_ 16384
#define D_ 512
#define H_ 1536
#define CM_ 192
#define KE_ 1344      // im2col K = 192*7
#define NFFT_ 1024
#define NF_ 513
#define HOP_ 256
#define NO2_ 1026
#define NPAD_ 1152    // head N padded to tile multiple
#define KI_ 1088      // ISTFT K (= 1026 padded to 64-multiple)
#define LOUT_ 524032

typedef _Float16 f16;
typedef f16 f16x8 __attribute__((ext_vector_type(8)));
typedef float f32x4 __attribute__((ext_vector_type(4)));

__device__ __forceinline__ float gelu_f(float v) {
    return 0.5f * v * (1.0f + erff(v * 0.70710678118654752f));
}

__device__ __forceinline__ void gload16(const void* g, void* s) {
    __builtin_amdgcn_global_load_lds((const __attribute__((address_space(1))) void*)g,
                                     (__attribute__((address_space(3))) void*)s, 16, 0, 0);
}

// ---------------- conversion / prep kernels ----------------

__global__ __launch_bounds__(256) void k_cvt(const float* __restrict__ src,
                                             f16* __restrict__ dst, int n) {
    int i = blockIdx.x * 256 + threadIdx.x;
    if (i < n) dst[i] = (f16)src[i];
}

// head weights (1026,512) -> fp16 (1152,512) zero-padded rows
__global__ __launch_bounds__(256) void k_cvt_head(const float* __restrict__ src,
                                                  f16* __restrict__ dst) {
    int i = blockIdx.x * 256 + threadIdx.x;
    if (i >= NPAD_ * D_) return;
    int row = i >> 9;
    dst[i] = (row < NO2_) ? (f16)src[i] : (f16)0.0f;
}

__global__ __launch_bounds__(256) void k_pad_hb(const float* __restrict__ src,
                                                float* __restrict__ dst) {
    int i = blockIdx.x * 256 + threadIdx.x;
    if (i < NPAD_) dst[i] = (i < NO2_) ? src[i] : 0.0f;
}

// dw (8,512,7) -> dwT[bl][k][d]
__global__ __launch_bounds__(256) void k_cvtdw(const float* __restrict__ dw,
                                               float* __restrict__ dwT) {
    int i = blockIdx.x * 256 + threadIdx.x;
    if (i >= 8 * 7 * 512) return;
    int bl = i / 3584;
    int rem = i - bl * 3584;
    int k = rem >> 9;
    int d = rem & 511;
    dwT[i] = dw[bl * 3584 + d * 7 + k];
}

// ISTFT basis fp16: wmat[n][f2], f2<513: cos*scale ; 513..1025: -sin*scale ; pad 0
__global__ __launch_bounds__(256) void k_build_wmat(f16* __restrict__ wmat) {
    int idx = blockIdx.x * 256 + threadIdx.x;
    if (idx >= NFFT_ * KI_) return;
    int n = idx / KI_;
    int f2 = idx - n * KI_;
    float v = 0.0f;
    if (f2 < NF_) {
        int r = (n * f2) & (NFFT_ - 1);
        float sc = (f2 == 0 || f2 == NF_ - 1) ? (1.0f / NFFT_) : (2.0f / NFFT_);
        v = cospif((float)r * (2.0f / NFFT_)) * sc;
    } else if (f2 < NO2_) {
        int f = f2 - NF_;
        int r = (n * f) & (NFFT_ - 1);
        float sc = (f == 0 || f == NF_ - 1) ? (1.0f / NFFT_) : (2.0f / NFFT_);
        v = -sinpif((float)r * (2.0f / NFFT_)) * sc;
    }
    wmat[idx] = (f16)v;
}

// im2col for embed conv: A[bt][c*7+k] = mel[b][c][t+k-3]
__global__ __launch_bounds__(256) void k_im2col(const float* __restrict__ mel,
                                                f16* __restrict__ A) {
    int idx = blockIdx.x * 256 + threadIdx.x;
    if (idx >= BT_ * KE_) return;
    int bt = idx / KE_;
    int ck = idx - bt * KE_;
    int c = ck / 7;
    int kk = ck - c * 7;
    int b = bt >> 11;
    int t = bt & (T_ - 1);
    int tt = t + kk - 3;
    float v = (tt >= 0 && tt < T_) ? mel[((size_t)b * CM_ + c) * T_ + tt] : 0.0f;
    A[idx] = (f16)v;
}

// ---------------- LayerNorm over D=512, one wave per row ----------------
template <bool HOUT>
__global__ __launch_bounds__(64) void k_ln(const float* __restrict__ in,
                                           void* __restrict__ out,
                                           const float* __restrict__ w,
                                           const float* __restrict__ b) {
    int row = blockIdx.x;
    int lane = threadIdx.x;
    const float* p = in + (size_t)row * D_ + lane * 8;
    float4 v0 = *(const float4*)p;
    float4 v1 = *(const float4*)(p + 4);
    float s  = v0.x + v0.y + v0.z + v0.w + v1.x + v1.y + v1.z + v1.w;
    float ss = v0.x * v0.x + v0.y * v0.y + v0.z * v0.z + v0.w * v0.w +
               v1.x * v1.x + v1.y * v1.y + v1.z * v1.z + v1.w * v1.w;
#pragma unroll
    for (int off = 32; off > 0; off >>= 1) {
        s  += __shfl_xor(s, off);
        ss += __shfl_xor(ss, off);
    }
    float mean = s * (1.0f / 512.0f);
    float var  = ss * (1.0f / 512.0f) - mean * mean;
    float rs = rsqrtf(var + 1e-5f);
    const float* wp = w + lane * 8;
    const float* bp = b + lane * 8;
    float4 w0 = *(const float4*)wp, w1 = *(const float4*)(wp + 4);
    float4 b0 = *(const float4*)bp, b1 = *(const float4*)(bp + 4);
    float o[8];
    o[0] = (v0.x - mean) * rs * w0.x + b0.x;
    o[1] = (v0.y - mean) * rs * w0.y + b0.y;
    o[2] = (v0.z - mean) * rs * w0.z + b0.z;
    o[3] = (v0.w - mean) * rs * w0.w + b0.w;
    o[4] = (v1.x - mean) * rs * w1.x + b1.x;
    o[5] = (v1.y - mean) * rs * w1.y + b1.y;
    o[6] = (v1.z - mean) * rs * w1.z + b1.z;
    o[7] = (v1.w - mean) * rs * w1.w + b1.w;
    if constexpr (HOUT) {
        f16x8 h;
#pragma unroll
        for (int i = 0; i < 8; ++i) h[i] = (f16)o[i];
        *(f16x8*)((f16*)out + (size_t)row * D_ + lane * 8) = h;
    } else {
        float* q = (float*)out + (size_t)row * D_ + lane * 8;
        *(float4*)q = make_float4(o[0], o[1], o[2], o[3]);
        *(float4*)(q + 4) = make_float4(o[4], o[5], o[6], o[7]);
    }
}

// ---------------- fused depthwise conv (k=7 over t) + LayerNorm -> fp16 ----------------
__global__ __launch_bounds__(64) void k_dwln(const float* __restrict__ x,
                                             const float* __restrict__ dwT,
                                             const float* __restrict__ db,
                                             const float* __restrict__ nw,
                                             const float* __restrict__ nb,
                                             f16* __restrict__ out) {
    int bt = blockIdx.x;
    int t = bt & (T_ - 1);
    int base = bt - t;
    int lane = threadIdx.x;
    int d0 = lane << 3;
    float a[8];
    *(float4*)&a[0] = *(const float4*)(db + d0);
    *(float4*)&a[4] = *(const float4*)(db + d0 + 4);
#pragma unroll
    for (int k = 0; k < 7; ++k) {
        int tt = t + k - 3;
        if (tt < 0 || tt >= T_) continue;
        const float* xp = x + (((size_t)(base + tt)) << 9) + d0;
        float4 x0 = *(const float4*)xp, x1 = *(const float4*)(xp + 4);
        const float* wp = dwT + (k << 9) + d0;
        float4 w0 = *(const float4*)wp, w1 = *(const float4*)(wp + 4);
        a[0] = fmaf(w0.x, x0.x, a[0]); a[1] = fmaf(w0.y, x0.y, a[1]);
        a[2] = fmaf(w0.z, x0.z, a[2]); a[3] = fmaf(w0.w, x0.w, a[3]);
        a[4] = fmaf(w1.x, x1.x, a[4]); a[5] = fmaf(w1.y, x1.y, a[5]);
        a[6] = fmaf(w1.z, x1.z, a[6]); a[7] = fmaf(w1.w, x1.w, a[7]);
    }
    float s = 0.f, ss = 0.f;
#pragma unroll
    for (int i = 0; i < 8; ++i) { s += a[i]; ss = fmaf(a[i], a[i], ss); }
#pragma unroll
    for (int off = 32; off > 0; off >>= 1) {
        s  += __shfl_xor(s, off);
        ss += __shfl_xor(ss, off);
    }
    float mean = s * (1.0f / 512.0f);
    float var  = ss * (1.0f / 512.0f) - mean * mean;
    float rs = rsqrtf(var + 1e-5f);
    float4 w0 = *(const float4*)(nw + d0), w1 = *(const float4*)(nw + d0 + 4);
    float4 b0 = *(const float4*)(nb + d0), b1 = *(const float4*)(nb + d0 + 4);
    f16x8 h;
    h[0] = (f16)((a[0] - mean) * rs * w0.x + b0.x);
    h[1] = (f16)((a[1] - mean) * rs * w0.y + b0.y);
    h[2] = (f16)((a[2] - mean) * rs * w0.z + b0.z);
    h[3] = (f16)((a[3] - mean) * rs * w0.w + b0.w);
    h[4] = (f16)((a[4] - mean) * rs * w1.x + b1.x);
    h[5] = (f16)((a[5] - mean) * rs * w1.y + b1.y);
    h[6] = (f16)((a[6] - mean) * rs * w1.z + b1.z);
    h[7] = (f16)((a[7] - mean) * rs * w1.w + b1.w);
    *(f16x8*)(out + ((size_t)bt << 9) + d0) = h;
}

// ---------------- 8-phase pipelined fp16 MFMA GEMM ----------------
// C(16384 x N) = A(16384 x K) . W(N x K)^T ;  BM=256, BN=128, BK=64
// LDS: 3-deep ring of {A 256x64, B 128x64} f16 tiles, XOR-swizzled (slot ^= row&7)
// via pre-swizzled global source (linear global_load_lds dest) + swizzled ds_read.
// Counted vmcnt(6): 6 load-instrs (tile t+2) in flight across barriers.
// EPI: 0 = fp32 +bias ; 1 = fp16 gelu(+bias) ; 2 = fp32 C += gamma*(v+bias) ; 3 = fp32 *bias

#define GA_ 16384   // f16 elems of A tile
#define GSTR_ 24576 // f16 elems per ring slot (A+B)

// one staging instruction: 64 rows x 64 cols, 512 threads x 16B
__device__ __forceinline__ void st64(const f16* __restrict__ g, f16* s,
                                     int row0, int K, int kof, int tid) {
    int rr = tid >> 3;
    int gs = (tid & 7) ^ (rr & 7);                       // pre-swizzled global slot
    gload16(g + (size_t)(row0 + rr) * K + kof + (gs << 3),
            s + ((size_t)(row0 + rr) << 6) + ((tid & 7) << 3));  // linear LDS dest
}

#define MF(d, a, b) d = __builtin_amdgcn_mfma_f32_16x16x32_f16(a, b, d, 0, 0, 0)
#define BAR() __builtin_amdgcn_s_barrier()
#define PRIO(x) __builtin_amdgcn_s_setprio(x)
#define RDA(off, sx) (*(const f16x8*)(sA + ((wm + (off) + lr) << 6) + (sx)))
#define RDB(off, sx) (*(const f16x8*)(sB + ((wn + (off) + lr) << 6) + (sx)))

template <int EPI>
__global__ __launch_bounds__(512, 2) void k_hgemm2(const f16* __restrict__ A,
                                                   const f16* __restrict__ W,
                                                   const float* __restrict__ bias,
                                                   const float* __restrict__ gamma,
                                                   void* __restrict__ C,
                                                   int K, int ldc, int nNt) {
    __shared__ f16 lds[3 * GSTR_];
    const int tid = threadIdx.x;
    int nwg = gridDim.x;
    int bid = blockIdx.x;
    int q = nwg >> 3, r = nwg & 7;
    int xcd = bid & 7, lin = bid >> 3;
    int swz = (xcd < r ? xcd * (q + 1) : r * (q + 1) + (xcd - r) * q) + lin;
    int nt = swz % nNt;
    int mt = swz / nNt;
    int bm = mt << 8;
    int bn = nt << 7;
    const f16* gA = A + (size_t)bm * K;
    const f16* gW = W + (size_t)bn * K;

    int lane = tid & 63;
    int wv = tid >> 6;
    int wm = (wv >> 1) << 6;   // 4 wave-rows of 64
    int wn = (wv & 1) << 6;    // 2 wave-cols of 64
    int lr = lane & 15;
    int lk = lane >> 4;
    int sx0 = ((lk ^ (lr & 7)) << 3);          // k-half 0 swizzled slot (f16 offset)
    int sx1 = (((lk + 4) ^ (lr & 7)) << 3);    // k-half 1

    f32x4 acc[4][4];
#pragma unroll
    for (int i = 0; i < 4; ++i)
#pragma unroll
        for (int j = 0; j < 4; ++j) acc[i][j] = {0.f, 0.f, 0.f, 0.f};

    int nk = K >> 6;
    f16* p0 = lds;               // tile t
    f16* p1 = lds + GSTR_;       // tile t+1
    f16* p2 = lds + 2 * GSTR_;   // staging dest (tile t+2)

    // prologue: stage tiles 0 and 1 (12 loads), wait for tile 0 (vmcnt(6))
    st64(gA, p0, 0, K, 0, tid);   st64(gA, p0, 64, K, 0, tid);
    st64(gA, p0, 128, K, 0, tid); st64(gA, p0, 192, K, 0, tid);
    st64(gW, p0 + GA_, 0, K, 0, tid); st64(gW, p0 + GA_, 64, K, 0, tid);
    st64(gA, p1, 0, K, 64, tid);   st64(gA, p1, 64, K, 64, tid);
    st64(gA, p1, 128, K, 64, tid); st64(gA, p1, 192, K, 64, tid);
    st64(gW, p1 + GA_, 0, K, 64, tid); st64(gW, p1 + GA_, 64, K, 64, tid);
    asm volatile("s_waitcnt vmcnt(6)" ::: "memory");
    BAR();

    for (int t = 0; t < nk; ++t) {
        f16* sA = p0;
        f16* sB = p0 + GA_;
        int t2 = t + 2;
        int ko2 = t2 << 6;
        bool stg = (t2 < nk);
        f16x8 b0, b1, b2, b3, a0, a1;
        // ---- phase 0: B[kh0] + A rows 0-31 [kh0]; stage A rows 0-127 of t+2
        b0 = RDB(0, sx0); b1 = RDB(16, sx0); b2 = RDB(32, sx0); b3 = RDB(48, sx0);
        a0 = RDA(0, sx0); a1 = RDA(16, sx0);
        if (stg) { st64(gA, p2, 0, K, ko2, tid); st64(gA, p2, 64, K, ko2, tid); }
        BAR(); PRIO(1);
        MF(acc[0][0], a0, b0); MF(acc[0][1], a0, b1); MF(acc[0][2], a0, b2); MF(acc[0][3], a0, b3);
        MF(acc[1][0], a1, b0); MF(acc[1][1], a1, b1); MF(acc[1][2], a1, b2); MF(acc[1][3], a1, b3);
        PRIO(0); BAR();
        // ---- phase 1: A rows 32-63 [kh0]; stage A rows 128-255 of t+2
        a0 = RDA(32, sx0); a1 = RDA(48, sx0);
        if (stg) { st64(gA, p2, 128, K, ko2, tid); st64(gA, p2, 192, K, ko2, tid); }
        BAR(); PRIO(1);
        MF(acc[2][0], a0, b0); MF(acc[2][1], a0, b1); MF(acc[2][2], a0, b2); MF(acc[2][3], a0, b3);
        MF(acc[3][0], a1, b0); MF(acc[3][1], a1, b1); MF(acc[3][2], a1, b2); MF(acc[3][3], a1, b3);
        PRIO(0); BAR();
        // ---- phase 2: B[kh1] + A rows 0-31 [kh1]; stage B of t+2
        b0 = RDB(0, sx1); b1 = RDB(16, sx1); b2 = RDB(32, sx1); b3 = RDB(48, sx1);
        a0 = RDA(0, sx1); a1 = RDA(16, sx1);
        if (stg) { st64(gW, p2 + GA_, 0, K, ko2, tid); st64(gW, p2 + GA_, 64, K, ko2, tid); }
        BAR(); PRIO(1);
        MF(acc[0][0], a0, b0); MF(acc[0][1], a0, b1); MF(acc[0][2], a0, b2); MF(acc[0][3], a0, b3);
        MF(acc[1][0], a1, b0); MF(acc[1][1], a1, b1); MF(acc[1][2], a1, b2); MF(acc[1][3], a1, b3);
        PRIO(0); BAR();
        // ---- phase 3: A rows 32-63 [kh1]; vmcnt gate for next tile
        a0 = RDA(32, sx1); a1 = RDA(48, sx1);
        BAR(); PRIO(1);
        MF(acc[2][0], a0, b0); MF(acc[2][1], a0, b1); MF(acc[2][2], a0, b2); MF(acc[2][3], a0, b3);
        MF(acc[3][0], a1, b0); MF(acc[3][1], a1, b1); MF(acc[3][2], a1, b2); MF(acc[3][3], a1, b3);
        PRIO(0);
        if (t2 < nk) asm volatile("s_waitcnt vmcnt(6)" ::: "memory");
        else if (t2 == nk) asm volatile("s_waitcnt vmcnt(0)" ::: "memory");
        BAR();
        f16* tmp = p0; p0 = p1; p1 = p2; p2 = tmp;
    }

    int lk4 = lk << 2;
#pragma unroll
    for (int i = 0; i < 4; ++i) {
#pragma unroll
        for (int rr = 0; rr < 4; ++rr) {
            int row = bm + wm + i * 16 + lk4 + rr;
            size_t moff = (size_t)row * ldc;
#pragma unroll
            for (int j = 0; j < 4; ++j) {
                int col = bn + wn + j * 16 + lr;
                float v = acc[i][j][rr];
                if constexpr (EPI == 0) {
                    ((float*)C)[moff + col] = v + bias[col];
                } else if constexpr (EPI == 1) {
                    ((f16*)C)[moff + col] = (f16)gelu_f(v + bias[col]);
                } else if constexpr (EPI == 2) {
                    ((float*)C)[moff + col] += gamma[col] * (v + bias[col]);
                } else {
                    ((float*)C)[moff + col] = v * bias[col];
                }
            }
        }
    }
}

// ---------------- head fp32 (stride 1152) -> S fp16 (stride 1088, padded) ----------------
__global__ __launch_bounds__(256) void k_srsi(const float* __restrict__ o,
                                              f16* __restrict__ S) {
    int idx = blockIdx.x * 256 + threadIdx.x;
    if (idx >= BT_ * KI_) return;
    int m = idx / KI_;
    int f2 = idx - m * KI_;
    size_t base = (size_t)m * NPAD_;
    float v = 0.0f;
    if (f2 < NF_) {
        float mag = fminf(expf(o[base + f2]), 100.0f);
        float sn, cs;
        sincosf(o[base + NF_ + f2], &sn, &cs);
        v = mag * cs;
    } else if (f2 < NO2_) {
        int f = f2 - NF_;
        float mag = fminf(expf(o[base + f]), 100.0f);
        float sn, cs;
        sincosf(o[base + NF_ + f], &sn, &cs);
        v = mag * sn;
    }
    S[idx] = (f16)v;
}

// ---------------- overlap-add + win_env + crop (deterministic gather) ----------------
__global__ __launch_bounds__(256) void k_gather(const float* __restrict__ frames,
                                                const float* __restrict__ win,
                                                float* __restrict__ out) {
    int idx = blockIdx.x * 256 + threadIdx.x;
    int b  = idx / LOUT_;
    int lp = idx - b * LOUT_;
    int l = lp + (NFFT_ / 2);
    int thi = l >> 8;
    if (thi > T_ - 1) thi = T_ - 1;
    int tlo = l - (NFFT_ - 1) + (HOP_ - 1);
    tlo = (tlo < 0) ? 0 : (tlo >> 8);
    float num = 0.0f, den = 0.0f;
    for (int t = tlo; t <= thi; ++t) {
        int n = l - (t << 8);
        float wv = win[n];
        num += frames[((size_t)(b * T_ + t) << 10) + n];
        den = fmaf(wv, wv, den);
    }
    out[idx] = num / (den + 1e-11f);
}

// ---------------- launch ----------------
extern "C" void kernel_launch(void* const* d_in, const int* in_sizes, int n_in,
                              void* d_out, int out_size, void* d_ws, size_t ws_size,
                              hipStream_t stream) {
    (void)in_sizes; (void)n_in; (void)out_size; (void)ws_size;
    const float* mel     = (const float*)d_in[0];
    const float* embed_w = (const float*)d_in[1];
    const float* embed_b = (const float*)d_in[2];
    const float* norm_w  = (const float*)d_in[3];
    const float* norm_b  = (const float*)d_in[4];
    const float* bdw = (const float*)d_in[5];
    const float* bdb = (const float*)d_in[6];
    const float* bnw = (const float*)d_in[7];
    const float* bnb = (const float*)d_in[8];
    const float* bw1 = (const float*)d_in[9];
    const float* bb1 = (const float*)d_in[10];
    const float* bw2 = (const float*)d_in[11];
    const float* bb2 = (const float*)d_in[12];
    const float* bg  = (const float*)d_in[13];
    const float* fnw = (const float*)d_in[14];
    const float* fnb = (const float*)d_in[15];
    const float* hw  = (const float*)d_in[16];
    const float* hb  = (const float*)d_in[17];
    const float* win = (const float*)d_in[18];

    char* ws = (char*)d_ws;
    // region A: [0, 50.3MB): xbuf fp32 (33.5MB) + ybuf_h fp16 (16.8MB); S_h (35.7MB) overlays later
    float* xbuf   = (float*)ws;
    f16*   ybuf_h = (f16*)(ws + 33554432);
    f16*   S_h    = (f16*)ws;
    // region R: [50.3MB, 134.2MB): hbuf_h fp16; also A_h / obuf / frames at base
    char* R = ws + 50331648;
    f16*   hbuf_h = (f16*)(R + 33554432);
    f16*   A_h    = (f16*)R;
    float* obuf   = (float*)R;
    float* frames = (float*)R;
    // region W: [134.2MB, ...): converted weights
    char* Wr = ws + 134217728;
    f16*   w1_h   = (f16*)Wr;                     // 12,582,912
    f16*   w2_h   = (f16*)(Wr + 12582912);        // 12,582,912
    f16*   head_h = (f16*)(Wr + 25165824);        // 1,179,648
    f16*   wmat_h = (f16*)(Wr + 26345472);        // 2,228,224
    f16*   we_h   = (f16*)(Wr + 28573696);        // 1,376,256
    float* hb_pad = (float*)(Wr + 29949952);      // 4,608
    float* dwT    = (float*)(Wr + 29954560);      // 114,688

    const int nW1 = 8 * H_ * D_;
    k_cvt<<<(nW1 + 255) / 256, 256, 0, stream>>>(bw1, w1_h, nW1);
    k_cvt<<<(nW1 + 255) / 256, 256, 0, stream>>>(bw2, w2_h, nW1);
    k_cvt<<<(CM_ * 7 * D_ + 255) / 256, 256, 0, stream>>>(embed_w, we_h, CM_ * 7 * D_);
    k_cvt_head<<<(NPAD_ * D_ + 255) / 256, 256, 0, stream>>>(hw, head_h);
    k_pad_hb<<<5, 256, 0, stream>>>(hb, hb_pad);
    k_cvtdw<<<(8 * 3584 + 255) / 256, 256, 0, stream>>>(bdw, dwT);
    k_build_wmat<<<(NFFT_ * KI_ + 255) / 256, 256, 0, stream>>>(wmat_h);

    // embed conv as im2col + GEMM
    k_im2col<<<(BT_ * KE_ + 255) / 256, 256, 0, stream>>>(mel, A_h);
    k_hgemm2<0><<<64 * 4, 512, 0, stream>>>(A_h, we_h, embed_b, nullptr, xbuf,
                                            KE_, D_, 4);
    k_ln<false><<<BT_, 64, 0, stream>>>(xbuf, xbuf, norm_w, norm_b);

    for (int bl = 0; bl < 8; ++bl) {
        k_dwln<<<BT_, 64, 0, stream>>>(xbuf, dwT + bl * 3584, bdb + bl * D_,
                                       bnw + bl * D_, bnb + bl * D_, ybuf_h);
        k_hgemm2<1><<<64 * 12, 512, 0, stream>>>(ybuf_h, w1_h + (size_t)bl * H_ * D_,
                                                 bb1 + bl * H_, nullptr, hbuf_h,
                                                 D_, H_, 12);
        k_hgemm2<2><<<64 * 4, 512, 0, stream>>>(hbuf_h, w2_h + (size_t)bl * D_ * H_,
                                                bb2 + bl * D_, bg + bl * D_, xbuf,
                                                H_, D_, 4);
    }

    k_ln<true><<<BT_, 64, 0, stream>>>(xbuf, ybuf_h, fnw, fnb);
    k_hgemm2<0><<<64 * 9, 512, 0, stream>>>(ybuf_h, head_h, hb_pad, nullptr, obuf,
                                            D_, NPAD_, 9);
    k_srsi<<<(BT_ * KI_ + 255) / 256, 256, 0, stream>>>(obuf, S_h);
    k_hgemm2<3><<<64 * 8, 512, 0, stream>>>(S_h, wmat_h, win, nullptr, frames,
                                            KI_, NFFT_, 8);
    k_gather<<<B_ * LOUT_ / 256, 256, 0, stream>>>(frames, win, (float*)d_out);
}